// Round 17
// baseline (137.495 us; speedup 1.0000x reference)
//
#include <hip/hip_runtime.h>
#include <stdint.h>

typedef unsigned short u16;
typedef __bf16 bf16x8 __attribute__((ext_vector_type(8)));
typedef float f32x4 __attribute__((ext_vector_type(4)));
typedef u16 u16x4 __attribute__((ext_vector_type(4)));
typedef u16 u16x8 __attribute__((ext_vector_type(8)));
typedef uint32_t u32x2 __attribute__((ext_vector_type(2)));

#define LDS_CAST(p) (reinterpret_cast<__attribute__((address_space(3))) uint32_t*>(reinterpret_cast<uintptr_t>(p)))
#define GLB_CAST(p) (reinterpret_cast<const __attribute__((address_space(1))) uint32_t*>(reinterpret_cast<uintptr_t>(p)))
#define GLOAD16(g, l) __builtin_amdgcn_global_load_lds(GLB_CAST(g), LDS_CAST(l), 16, 0, 0)
#define AS3U16(p) (reinterpret_cast<__attribute__((address_space(3))) u16*>(reinterpret_cast<uintptr_t>(p)))

__device__ __forceinline__ u16 f2bf(float f) {
    uint32_t u = __builtin_bit_cast(uint32_t, f);
    u += 0x7fffu + ((u >> 16) & 1u);   // RNE
    return (u16)(u >> 16);
}
__device__ __forceinline__ u16 bfbits(float f) {   // native cvt
    return __builtin_bit_cast(u16, (__bf16)f);
}

// ---------------------------------------------------------------- fused casts: x (blocks 0..6143) + 4 weights
__global__ void cast_all(const float* __restrict__ x,
                         const float* __restrict__ a, const float* __restrict__ b,
                         const float* __restrict__ c, const float* __restrict__ d,
                         u16* __restrict__ ox, u16* __restrict__ oa, u16* __restrict__ ob,
                         u16* __restrict__ oc, u16* __restrict__ od) {
    const int bid = blockIdx.x;
    const float* in;
    u16* out;
    int i;
    if (bid < 6144) {
        in = x; out = ox; i = bid * 256 + threadIdx.x;
    } else {
        const int zb = bid - 6144;
        const int z = zb / 576, lb = zb % 576;
        in = (z == 0) ? a : (z == 1) ? b : (z == 2) ? c : d;
        out = (z == 0) ? oa : (z == 1) ? ob : (z == 2) ? oc : od;
        i = lb * 256 + threadIdx.x;
    }
    float4 f = reinterpret_cast<const float4*>(in)[i];
    u16x4 o;
    o.x = f2bf(f.x); o.y = f2bf(f.y); o.z = f2bf(f.z); o.w = f2bf(f.w);
    reinterpret_cast<u16x4*>(out)[i] = o;
}

// ---------------------------------------------------------------- fused QKV projection
// z-FUSED: one block stages its 128-row X panel ONCE and computes Q,K,V tiles together
// (3x MFMA per staged byte; barriers/vmcnt per MFMA /3). 2-buffer counted-vmcnt pipeline;
// XCD remap. q,k [B,H,S,Dh] (q pre-scaled log2e/8); v TRANSPOSED [B,H,Dh,S].
__global__ __launch_bounds__(256, 2) void gemm_qkv(
    const u16* __restrict__ X, const u16* __restrict__ Wq,
    const u16* __restrict__ Wk, const u16* __restrict__ Wv,
    u16* __restrict__ qo, u16* __restrict__ ko, u16* __restrict__ vTo)
{
    __shared__ u16 As[2][128 * 32];        // 16 KB
    __shared__ u16 Bs[3][2][128 * 32];     // 48 KB
    const int tid = threadIdx.x;
    const int lane = tid & 63;
    const int w = tid >> 6;
    const int lr = lane & 15, lg = lane >> 4;
    const int wrow = (w >> 1) * 64, wcol = (w & 1) * 64;

    // XCD remap (T1): 384 blocks; each XCD owns row-panels [xcd*8, xcd*8+8)
    const int lin = blockIdx.x + blockIdx.y * 6;
    const int xcd = lin & 7, idx = lin >> 3;      // idx in [0,48)
    const int prow = xcd * 8 + idx / 6;           // row panel 0..63
    const int bxc = idx % 6;
    const int row0 = prow * 128, col0 = bxc * 128;

    f32x4 acc[3][4][4];
#pragma unroll
    for (int zz = 0; zz < 3; ++zz)
#pragma unroll
        for (int m = 0; m < 4; ++m)
#pragma unroll
            for (int n = 0; n < 4; ++n)
#pragma unroll
                for (int j = 0; j < 4; ++j) acc[zz][m][n][j] = 0.f;

    // 8 gloads/thread/step: 2 for X, 2 per weight.
#define QSTAGE(KT)                                                                                 \
    {                                                                                              \
        const int buf_ = (KT) & 1;                                                                 \
        _Pragma("unroll")                                                                          \
        for (int it = 0; it < 2; ++it) {                                                           \
            const int c = it * 256 + w * 64 + lane;                                                \
            const int row = c >> 2, c16 = c & 3;                                                   \
            const size_t go = (size_t)row * 768 + (KT) * 32 + c16 * 8;                             \
            const int lo = (it * 256 + w * 64) * 8;                                                \
            GLOAD16(X  + (size_t)row0 * 768 + go, &As[buf_][lo]);                                  \
            GLOAD16(Wq + (size_t)col0 * 768 + go, &Bs[0][buf_][lo]);                               \
            GLOAD16(Wk + (size_t)col0 * 768 + go, &Bs[1][buf_][lo]);                               \
            GLOAD16(Wv + (size_t)col0 * 768 + go, &Bs[2][buf_][lo]);                               \
        }                                                                                          \
    }

#define QSTEP(KT, VN, PF)                                                                          \
    {                                                                                              \
        if (PF) QSTAGE((KT) + 1);                                                                  \
        asm volatile("s_waitcnt vmcnt(" #VN ")" ::: "memory");                                     \
        __builtin_amdgcn_s_barrier();                                                              \
        const int cur_ = (KT) & 1;                                                                 \
        bf16x8 af[4];                                                                              \
        _Pragma("unroll")                                                                          \
        for (int m = 0; m < 4; ++m) af[m] = *(const bf16x8*)&As[cur_][(wrow + m * 16 + lr) * 32 + lg * 8]; \
        _Pragma("unroll")                                                                          \
        for (int zz = 0; zz < 3; ++zz) {                                                           \
            bf16x8 bfr[4];                                                                         \
            _Pragma("unroll")                                                                      \
            for (int n = 0; n < 4; ++n) bfr[n] = *(const bf16x8*)&Bs[zz][cur_][(wcol + n * 16 + lr) * 32 + lg * 8]; \
            _Pragma("unroll")                                                                      \
            for (int m = 0; m < 4; ++m)                                                            \
                _Pragma("unroll")                                                                  \
                for (int n = 0; n < 4; ++n)                                                        \
                    acc[zz][m][n] = __builtin_amdgcn_mfma_f32_16x16x32_bf16(af[m], bfr[n], acc[zz][m][n], 0, 0, 0); \
        }                                                                                          \
        asm volatile("s_waitcnt lgkmcnt(0)" ::: "memory");                                         \
        __builtin_amdgcn_sched_barrier(0);                                                         \
        __builtin_amdgcn_s_barrier();                                                              \
    }

    QSTAGE(0);
    for (int kt = 0; kt < 23; ++kt) QSTEP(kt, 8, true);
    QSTEP(23, 0, false);
#undef QSTEP
#undef QSTAGE

    // epilogue: z=0 -> q (scaled), z=1 -> k, z=2 -> v transposed
#pragma unroll
    for (int zz = 0; zz < 2; ++zz) {
        u16* outp = (zz == 0) ? qo : ko;
        const float scl = (zz == 0) ? 0.18033688011112042f : 1.0f;   // log2(e)/8
#pragma unroll
        for (int n = 0; n < 4; ++n) {
            const int j = col0 + wcol + n * 16 + lr;
            const int h = j >> 6, dh = j & 63;
#pragma unroll
            for (int m = 0; m < 4; ++m)
#pragma unroll
                for (int r = 0; r < 4; ++r) {
                    const int i = row0 + wrow + m * 16 + lg * 4 + r;
                    const int b = i >> 11, s = i & 2047;
                    outp[(((size_t)b * 12 + h) * 2048 + s) * 64 + dh] = bfbits(acc[zz][m][n][r] * scl);
                }
        }
    }
    {
#pragma unroll
        for (int n = 0; n < 4; ++n) {
            const int j = col0 + wcol + n * 16 + lr;
            const int h = j >> 6, dh = j & 63;
#pragma unroll
            for (int m = 0; m < 4; ++m) {
                const int i0 = row0 + wrow + m * 16 + lg * 4;
                const int b = i0 >> 11, s0 = i0 & 2047;
                u16x4 pk;
#pragma unroll
                for (int r = 0; r < 4; ++r) pk[r] = bfbits(acc[2][m][n][r]);
                *(u16x4*)&vTo[(((size_t)b * 12 + h) * 64 + dh) * 2048 + s0] = pk;
            }
        }
    }
}

// ---------------------------------------------------------------- causal flash attention
// (R7 step internals — unchanged) Fixed-max softmax: P = exp2(S'), per-lane partial row-sums,
// one reduce at end. P via transposed LDS [kv][16 q] + ds_read_b64_tr_b16.
template<bool DIAG>
__device__ __forceinline__ void attn_step(
    const bf16x8* aq, f32x4* o, float* lrow,
    const u16* __restrict__ Ksb, const u16* __restrict__ Vsb, u16* __restrict__ PT,
    int kvb, int qg0, int lr, int lg)
{
    // S = Q K^T  (q = lg*4+r, kv = n*16+lr)
    f32x4 sacc[4];
#pragma unroll
    for (int n = 0; n < 4; ++n)
#pragma unroll
        for (int j = 0; j < 4; ++j) sacc[n][j] = 0.f;
    __builtin_amdgcn_s_setprio(1);
#pragma unroll
    for (int kk = 0; kk < 2; ++kk)
#pragma unroll
        for (int n = 0; n < 4; ++n) {
            const int row = n * 16 + lr;
            const int p = (kk * 4 + lg) ^ (row & 7);
            bf16x8 bk = *(const bf16x8*)&Ksb[row * 64 + p * 8];
            sacc[n] = __builtin_amdgcn_mfma_f32_16x16x32_bf16(aq[kk], bk, sacc[n], 0, 0, 0);
        }
    __builtin_amdgcn_s_setprio(0);

    float pv[4][4];
#pragma unroll
    for (int r = 0; r < 4; ++r) {
        float ls = 0.f;
#pragma unroll
        for (int n = 0; n < 4; ++n) {
            float sv = sacc[n][r];
            if (DIAG && (kvb + n * 16 + lr) > qg0 + r) sv = -1e30f;   // exp2 -> 0
            const float e = __builtin_amdgcn_exp2f(sv);
            pv[r][n] = e;
            ls += e;
        }
        lrow[r] += ls;
    }

    // P^T -> LDS [kv][16 q]: fixed n, r=0..3 are q-contiguous -> one b64 write each
#pragma unroll
    for (int n = 0; n < 4; ++n) {
        u16x4 pk;
#pragma unroll
        for (int r = 0; r < 4; ++r) pk[r] = bfbits(pv[r][n]);
        *(u16x4*)&PT[(n * 16 + lr) * 16 + lg * 4] = pk;
    }

    // re-fragment via HW transpose read: lane(lr,lg) gets P[q=lr][kv=lg*8+j] per read
    u32x2 t0, t1, t2, t3;
    __attribute__((address_space(3))) u16* pb = AS3U16(PT) + lg * 128 + lr * 4;
    asm volatile("ds_read_b64_tr_b16 %0, %1" : "=v"(t0) : "v"(pb) : "memory");
    asm volatile("ds_read_b64_tr_b16 %0, %1 offset:128" : "=v"(t1) : "v"(pb) : "memory");
    asm volatile("ds_read_b64_tr_b16 %0, %1 offset:1024" : "=v"(t2) : "v"(pb) : "memory");
    asm volatile("ds_read_b64_tr_b16 %0, %1 offset:1152" : "=v"(t3) : "v"(pb) : "memory");
    asm volatile("s_waitcnt lgkmcnt(0)" ::: "memory");
    __builtin_amdgcn_sched_barrier(0);
    union { u32x2 h[2]; bf16x8 v; } ua, ub;
    ua.h[0] = t0; ua.h[1] = t1;
    ub.h[0] = t2; ub.h[1] = t3;
    const bf16x8 ap0 = ua.v, ap1 = ub.v;

    __builtin_amdgcn_s_setprio(1);
#pragma unroll
    for (int n = 0; n < 4; ++n) {
        const int rowv = n * 16 + lr;
        const int p0 = (0 + lg) ^ (rowv & 7);
        const int p1 = (4 + lg) ^ (rowv & 7);
        bf16x8 bv0 = *(const bf16x8*)&Vsb[rowv * 64 + p0 * 8];
        bf16x8 bv1 = *(const bf16x8*)&Vsb[rowv * 64 + p1 * 8];
        o[n] = __builtin_amdgcn_mfma_f32_16x16x32_bf16(ap0, bv0, o[n], 0, 0, 0);
        o[n] = __builtin_amdgcn_mfma_f32_16x16x32_bf16(ap1, bv1, o[n], 0, 0, 0);
    }
    __builtin_amdgcn_s_setprio(0);
}

// Causal, pair-balanced, XCD-swizzled. KVBLK=128 staging: two 64-kv tiles per sync
// (halved barrier count; odd steps barrier-free -> waves de-lockstep). attn_step unchanged.
__global__ __launch_bounds__(256) void attn_kernel(
    const u16* __restrict__ q, const u16* __restrict__ k,
    const u16* __restrict__ vT, u16* __restrict__ attn)
{
    __shared__ u16 Ks[2][2][64 * 64];   // [buf][half] 32 KB
    __shared__ u16 Vs[2][2][64 * 64];   // 32 KB
    __shared__ u16 Ps[4][64 * 16];      // per-wave P^T, 8 KB

    // XCD swizzle (T1): lin -> (lin%8)*96 + lin/8  (bijective, 768 blocks)
    const int lin = blockIdx.x + (blockIdx.y << 4);
    const int logi = (lin & 7) * 96 + (lin >> 3);
    const int pair = logi & 15, bh = logi >> 4;

    const int qA = pair, qB = 31 - pair;   // qA <= 15 < 16 <= qB
    const int tid = threadIdx.x, lane = tid & 63, w = tid >> 6;
    const int lr = lane & 15, lg = lane >> 4;

    const u16* Kp = k + (size_t)bh * 2048 * 64;
    const u16* Vp = vT + (size_t)bh * 64 * 2048;

    const u16* QpA = q + ((size_t)bh * 2048 + qA * 64 + w * 16) * 64;
    const u16* QpB = q + ((size_t)bh * 2048 + qB * 64 + w * 16) * 64;
    bf16x8 aqA[2], aqB[2];
    aqA[0] = *(const bf16x8*)&QpA[lr * 64 + lg * 8];
    aqA[1] = *(const bf16x8*)&QpA[lr * 64 + 32 + lg * 8];
    aqB[0] = *(const bf16x8*)&QpB[lr * 64 + lg * 8];
    aqB[1] = *(const bf16x8*)&QpB[lr * 64 + 32 + lg * 8];

    f32x4 oA[4], oB[4];
    float lA[4], lB[4];
#pragma unroll
    for (int n = 0; n < 4; ++n)
#pragma unroll
        for (int j = 0; j < 4; ++j) { oA[n][j] = 0.f; oB[n][j] = 0.f; }
#pragma unroll
    for (int r = 0; r < 4; ++r) { lA[r] = 0.f; lB[r] = 0.f; }

    // stage 64-kv tiles T and T+1 (clamped) into halves 0,1 of BUF; 8 gloads/thread
#define STAGE128(T, BUF)                                                                      \
    {                                                                                         \
        _Pragma("unroll")                                                                     \
        for (int hh = 0; hh < 2; ++hh) {                                                      \
            const int tt = ((T) + hh <= 31) ? (T) + hh : 31;                                  \
            _Pragma("unroll")                                                                 \
            for (int it = 0; it < 2; ++it) {                                                  \
                const int c = it * 256 + w * 64 + lane;                                       \
                const int row = c >> 3, pc = c & 7;                                           \
                const int lc = pc ^ (row & 7);                                                \
                GLOAD16(Kp + (size_t)(tt * 64 + row) * 64 + lc * 8, &Ks[BUF][hh][(it * 256 + w * 64) * 8]); \
                GLOAD16(Vp + (size_t)row * 2048 + tt * 64 + lc * 8, &Vs[BUF][hh][(it * 256 + w * 64) * 8]); \
            }                                                                                 \
        }                                                                                     \
    }

    // per-step sync/stage keyed on t parity: sync (drains stage issued 2 tiles ago),
    // then prefetch the pair t+2,t+3 into the other buffer.
#define TILE_CTL(T)                                                                           \
    const int buf_ = ((T) >> 1) & 1, half_ = (T) & 1;                                         \
    if (half_ == 0) {                                                                         \
        __syncthreads();                                                                      \
        if ((T) + 2 <= qB) STAGE128((T) + 2, buf_ ^ 1);                                       \
    }

    STAGE128(0, 0);
    const int qg0A = qA * 64 + w * 16 + lg * 4;
    const int qg0B = qB * 64 + w * 16 + lg * 4;

    int t = 0;
    for (; t < qA; ++t) {               // both tiles, no masking
        TILE_CTL(t);
        attn_step<false>(aqB, oB, lB, Ks[buf_][half_], Vs[buf_][half_], Ps[w], t * 64, qg0B, lr, lg);
        attn_step<false>(aqA, oA, lA, Ks[buf_][half_], Vs[buf_][half_], Ps[w], t * 64, qg0A, lr, lg);
    }
    {                                   // t == qA: A's diagonal
        TILE_CTL(t);
        attn_step<false>(aqB, oB, lB, Ks[buf_][half_], Vs[buf_][half_], Ps[w], t * 64, qg0B, lr, lg);
        attn_step<true >(aqA, oA, lA, Ks[buf_][half_], Vs[buf_][half_], Ps[w], t * 64, qg0A, lr, lg);
        ++t;
    }
    for (; t < qB; ++t) {               // B only, no masking
        TILE_CTL(t);
        attn_step<false>(aqB, oB, lB, Ks[buf_][half_], Vs[buf_][half_], Ps[w], t * 64, qg0B, lr, lg);
    }
    {                                   // t == qB: B's diagonal
        TILE_CTL(t);
        attn_step<true >(aqB, oB, lB, Ks[buf_][half_], Vs[buf_][half_], Ps[w], t * 64, qg0B, lr, lg);
    }
#undef TILE_CTL
#undef STAGE128

    // single end-of-kernel cross-lane reduce of the partial row-sums (lanes lr 0..15)
#pragma unroll
    for (int r = 0; r < 4; ++r) {
#pragma unroll
        for (int off = 1; off < 16; off <<= 1) {
            lA[r] += __shfl_xor(lA[r], off);
            lB[r] += __shfl_xor(lB[r], off);
        }
        lA[r] = 1.f / lA[r];
        lB[r] = 1.f / lB[r];
    }

    const int b = bh / 12, h = bh - b * 12;
#pragma unroll
    for (int n = 0; n < 4; ++n)
#pragma unroll
        for (int r = 0; r < 4; ++r) {
            const int sA = qA * 64 + w * 16 + lg * 4 + r;
            const int sB = qB * 64 + w * 16 + lg * 4 + r;
            attn[((size_t)b * 2048 + sA) * 768 + h * 64 + n * 16 + lr] = bfbits(oA[n][r] * lA[r]);
            attn[((size_t)b * 2048 + sB) * 768 + h * 64 + n * 16 + lr] = bfbits(oB[n][r] * lB[r]);
        }
}

// ---------------------------------------------------------------- output projection + bias (f32 out)
// BM=64 x BN=128; 2-buffer counted-vmcnt + XCD remap.
__global__ __launch_bounds__(256) void gemm_out(
    const u16* __restrict__ A, const u16* __restrict__ Wo,
    const float* __restrict__ bo, float* __restrict__ out)
{
    __shared__ u16 As[2][64 * 32];
    __shared__ u16 Bs[2][128 * 32];
    const int tid = threadIdx.x;
    const int lane = tid & 63;
    const int w = tid >> 6;
    const int lr = lane & 15, lg = lane >> 4;
    const int wrow = (w >> 1) * 32, wcol = (w & 1) * 64;   // wave tile 32x64

    // XCD remap: 768 blocks; each XCD owns row-panels [xcd*16, xcd*16+16)
    const int lin = blockIdx.x + blockIdx.y * 6;
    const int xcd = lin & 7, idx = lin >> 3;      // idx in [0,96)
    const int prow = xcd * 16 + idx / 6;          // row panel 0..127 (64 rows each)
    const int bxc = idx % 6;
    const int row0 = prow * 64, col0 = bxc * 128;

    f32x4 acc[2][4];
#pragma unroll
    for (int m = 0; m < 2; ++m)
#pragma unroll
        for (int n = 0; n < 4; ++n)
#pragma unroll
            for (int j = 0; j < 4; ++j) acc[m][n][j] = 0.f;

#define OSTAGE(KT)                                                                                 \
    {                                                                                              \
        const int buf_ = (KT) & 1;                                                                 \
        {   /* A tile: 64x32 = one gload */                                                        \
            const int c = w * 64 + lane;                                                           \
            const int row = c >> 2, c16 = c & 3;                                                   \
            GLOAD16(A + (size_t)(row0 + row) * 768 + (KT) * 32 + c16 * 8, &As[buf_][c * 8]);       \
        }                                                                                          \
        _Pragma("unroll")                                                                          \
        for (int it = 0; it < 2; ++it) {   /* B tile: 128x32 = two gloads */                       \
            const int c = it * 256 + w * 64 + lane;                                                \
            const int row = c >> 2, c16 = c & 3;                                                   \
            GLOAD16(Wo + (size_t)(col0 + row) * 768 + (KT) * 32 + c16 * 8, &Bs[buf_][c * 8]);      \
        }                                                                                          \
    }

#define OSTEP(KT, VN, PF)                                                                          \
    {                                                                                              \
        if (PF) OSTAGE((KT) + 1);                                                                  \
        asm volatile("s_waitcnt vmcnt(" #VN ")" ::: "memory");                                     \
        __builtin_amdgcn_s_barrier();                                                              \
        const int cur_ = (KT) & 1;                                                                 \
        bf16x8 af[2], bfr[4];                                                                      \
        _Pragma("unroll")                                                                          \
        for (int m = 0; m < 2; ++m) af[m] = *(const bf16x8*)&As[cur_][(wrow + m * 16 + lr) * 32 + lg * 8]; \
        _Pragma("unroll")                                                                          \
        for (int n = 0; n < 4; ++n) bfr[n] = *(const bf16x8*)&Bs[cur_][(wcol + n * 16 + lr) * 32 + lg * 8]; \
        asm volatile("s_waitcnt lgkmcnt(0)" ::: "memory");                                         \
        __builtin_amdgcn_sched_barrier(0);                                                         \
        __builtin_amdgcn_s_barrier();                                                              \
        _Pragma("unroll")                                                                          \
        for (int m = 0; m < 2; ++m)                                                                \
            _Pragma("unroll")                                                                      \
            for (int n = 0; n < 4; ++n)                                                            \
                acc[m][n] = __builtin_amdgcn_mfma_f32_16x16x32_bf16(af[m], bfr[n], acc[m][n], 0, 0, 0); \
    }

    OSTAGE(0);
    for (int kt = 0; kt < 23; ++kt) OSTEP(kt, 3, true);
    OSTEP(23, 0, false);
#undef OSTEP
#undef OSTAGE

#pragma unroll
    for (int n = 0; n < 4; ++n) {
        const int j = col0 + wcol + n * 16 + lr;
        const float bj = bo[j];
#pragma unroll
        for (int m = 0; m < 2; ++m)
#pragma unroll
            for (int r = 0; r < 4; ++r) {
                const int i = row0 + wrow + m * 16 + lg * 4 + r;
                out[(size_t)i * 768 + j] = acc[m][n][r] + bj;
            }
    }
}

// ---------------------------------------------------------------- launch
extern "C" void kernel_launch(void* const* d_in, const int* in_sizes, int n_in,
                              void* d_out, int out_size, void* d_ws, size_t ws_size,
                              hipStream_t stream) {
    const float* x  = (const float*)d_in[0];
    const float* Wq = (const float*)d_in[1];
    const float* Wk = (const float*)d_in[2];
    const float* Wv = (const float*)d_in[3];
    const float* Wo = (const float*)d_in[4];
    const float* bo = (const float*)d_in[5];
    float* out = (float*)d_out;

    // workspace layout (bf16 elements)
    const size_t NX = 6291456;   // 8192*768
    const size_t NW = 589824;    // 768*768
    if (ws_size < (NX * 4 + NW * 4 + NX) * sizeof(u16)) return;
    u16* ws  = (u16*)d_ws;
    u16* xb  = ws;
    u16* wqb = xb  + NX;
    u16* wkb = wqb + NW;
    u16* wvb = wkb + NW;
    u16* wob = wvb + NW;
    u16* qb_ = wob + NW;
    u16* kb_ = qb_ + NX;
    u16* vtb = kb_ + NX;
    u16* ab_ = vtb + NX;

    cast_all<<<6144 + 2304, 256, 0, stream>>>(x, Wq, Wk, Wv, Wo, xb, wqb, wkb, wvb, wob);

    gemm_qkv<<<dim3(6, 64), 256, 0, stream>>>(xb, wqb, wkb, wvb, qb_, kb_, vtb);
    attn_kernel<<<dim3(16, 48), 256, 0, stream>>>(qb_, kb_, vtb, ab_);
    gemm_out<<<dim3(6, 128), 256, 0, stream>>>(ab_, wob, bo, out);
}

// Round 18
// 120.554 us; speedup vs baseline: 1.1405x; 1.1405x over previous
//
#include <hip/hip_runtime.h>
#include <stdint.h>

typedef unsigned short u16;
typedef __bf16 bf16x8 __attribute__((ext_vector_type(8)));
typedef float f32x4 __attribute__((ext_vector_type(4)));
typedef u16 u16x4 __attribute__((ext_vector_type(4)));
typedef u16 u16x8 __attribute__((ext_vector_type(8)));
typedef uint32_t u32x2 __attribute__((ext_vector_type(2)));

#define LDS_CAST(p) (reinterpret_cast<__attribute__((address_space(3))) uint32_t*>(reinterpret_cast<uintptr_t>(p)))
#define GLB_CAST(p) (reinterpret_cast<const __attribute__((address_space(1))) uint32_t*>(reinterpret_cast<uintptr_t>(p)))
#define GLOAD16(g, l) __builtin_amdgcn_global_load_lds(GLB_CAST(g), LDS_CAST(l), 16, 0, 0)
#define AS3U16(p) (reinterpret_cast<__attribute__((address_space(3))) u16*>(reinterpret_cast<uintptr_t>(p)))

__device__ __forceinline__ u16 f2bf(float f) {
    uint32_t u = __builtin_bit_cast(uint32_t, f);
    u += 0x7fffu + ((u >> 16) & 1u);   // RNE
    return (u16)(u >> 16);
}
__device__ __forceinline__ u16 bfbits(float f) {   // native cvt
    return __builtin_bit_cast(u16, (__bf16)f);
}

// ---------------------------------------------------------------- fused casts: x (blocks 0..6143) + 4 weights
__global__ void cast_all(const float* __restrict__ x,
                         const float* __restrict__ a, const float* __restrict__ b,
                         const float* __restrict__ c, const float* __restrict__ d,
                         u16* __restrict__ ox, u16* __restrict__ oa, u16* __restrict__ ob,
                         u16* __restrict__ oc, u16* __restrict__ od) {
    const int bid = blockIdx.x;
    const float* in;
    u16* out;
    int i;
    if (bid < 6144) {
        in = x; out = ox; i = bid * 256 + threadIdx.x;
    } else {
        const int zb = bid - 6144;
        const int z = zb / 576, lb = zb % 576;
        in = (z == 0) ? a : (z == 1) ? b : (z == 2) ? c : d;
        out = (z == 0) ? oa : (z == 1) ? ob : (z == 2) ? oc : od;
        i = lb * 256 + threadIdx.x;
    }
    float4 f = reinterpret_cast<const float4*>(in)[i];
    u16x4 o;
    o.x = f2bf(f.x); o.y = f2bf(f.y); o.z = f2bf(f.z); o.w = f2bf(f.w);
    reinterpret_cast<u16x4*>(out)[i] = o;
}

// ---------------------------------------------------------------- fused QKV projection
// z-FUSED: one block stages its 128-row X panel ONCE and computes Q,K,V tiles together
// (3x MFMA per staged byte; barriers/vmcnt per MFMA /3). 2-buffer counted-vmcnt pipeline;
// XCD remap. q,k [B,H,S,Dh] (q pre-scaled log2e/8); v TRANSPOSED [B,H,Dh,S].
__global__ __launch_bounds__(256, 2) void gemm_qkv(
    const u16* __restrict__ X, const u16* __restrict__ Wq,
    const u16* __restrict__ Wk, const u16* __restrict__ Wv,
    u16* __restrict__ qo, u16* __restrict__ ko, u16* __restrict__ vTo)
{
    __shared__ u16 As[2][128 * 32];        // 16 KB
    __shared__ u16 Bs[3][2][128 * 32];     // 48 KB
    const int tid = threadIdx.x;
    const int lane = tid & 63;
    const int w = tid >> 6;
    const int lr = lane & 15, lg = lane >> 4;
    const int wrow = (w >> 1) * 64, wcol = (w & 1) * 64;

    // XCD remap (T1): 384 blocks; each XCD owns row-panels [xcd*8, xcd*8+8)
    const int lin = blockIdx.x + blockIdx.y * 6;
    const int xcd = lin & 7, idx = lin >> 3;      // idx in [0,48)
    const int prow = xcd * 8 + idx / 6;           // row panel 0..63
    const int bxc = idx % 6;
    const int row0 = prow * 128, col0 = bxc * 128;

    f32x4 acc[3][4][4];
#pragma unroll
    for (int zz = 0; zz < 3; ++zz)
#pragma unroll
        for (int m = 0; m < 4; ++m)
#pragma unroll
            for (int n = 0; n < 4; ++n)
#pragma unroll
                for (int j = 0; j < 4; ++j) acc[zz][m][n][j] = 0.f;

    // 8 gloads/thread/step: 2 for X, 2 per weight.
#define QSTAGE(KT)                                                                                 \
    {                                                                                              \
        const int buf_ = (KT) & 1;                                                                 \
        _Pragma("unroll")                                                                          \
        for (int it = 0; it < 2; ++it) {                                                           \
            const int c = it * 256 + w * 64 + lane;                                                \
            const int row = c >> 2, c16 = c & 3;                                                   \
            const size_t go = (size_t)row * 768 + (KT) * 32 + c16 * 8;                             \
            const int lo = (it * 256 + w * 64) * 8;                                                \
            GLOAD16(X  + (size_t)row0 * 768 + go, &As[buf_][lo]);                                  \
            GLOAD16(Wq + (size_t)col0 * 768 + go, &Bs[0][buf_][lo]);                               \
            GLOAD16(Wk + (size_t)col0 * 768 + go, &Bs[1][buf_][lo]);                               \
            GLOAD16(Wv + (size_t)col0 * 768 + go, &Bs[2][buf_][lo]);                               \
        }                                                                                          \
    }

    // STAGE(t+1) first (buf freed by step t-1's final barrier); vmcnt(8) retires stage t
    // (t+1's 8 loads remain in flight across the whole compute phase). All LDS reads of
    // buf cur drain before the final barrier (stage t+2 overwrites cur at step t+1's top).
#define QSTEP(KT, VN, PF)                                                                          \
    {                                                                                              \
        if (PF) QSTAGE((KT) + 1);                                                                  \
        asm volatile("s_waitcnt vmcnt(" #VN ")" ::: "memory");                                     \
        __builtin_amdgcn_s_barrier();                                                              \
        const int cur_ = (KT) & 1;                                                                 \
        bf16x8 af[4];                                                                              \
        _Pragma("unroll")                                                                          \
        for (int m = 0; m < 4; ++m) af[m] = *(const bf16x8*)&As[cur_][(wrow + m * 16 + lr) * 32 + lg * 8]; \
        _Pragma("unroll")                                                                          \
        for (int zz = 0; zz < 3; ++zz) {                                                           \
            bf16x8 bfr[4];                                                                         \
            _Pragma("unroll")                                                                      \
            for (int n = 0; n < 4; ++n) bfr[n] = *(const bf16x8*)&Bs[zz][cur_][(wcol + n * 16 + lr) * 32 + lg * 8]; \
            _Pragma("unroll")                                                                      \
            for (int m = 0; m < 4; ++m)                                                            \
                _Pragma("unroll")                                                                  \
                for (int n = 0; n < 4; ++n)                                                        \
                    acc[zz][m][n] = __builtin_amdgcn_mfma_f32_16x16x32_bf16(af[m], bfr[n], acc[zz][m][n], 0, 0, 0); \
        }                                                                                          \
        asm volatile("s_waitcnt lgkmcnt(0)" ::: "memory");                                         \
        __builtin_amdgcn_sched_barrier(0);                                                         \
        __builtin_amdgcn_s_barrier();                                                              \
    }

    QSTAGE(0);
    for (int kt = 0; kt < 23; ++kt) QSTEP(kt, 8, true);
    QSTEP(23, 0, false);
#undef QSTEP
#undef QSTAGE

    // epilogue: z=0 -> q (scaled), z=1 -> k, z=2 -> v transposed
#pragma unroll
    for (int zz = 0; zz < 2; ++zz) {
        u16* outp = (zz == 0) ? qo : ko;
        const float scl = (zz == 0) ? 0.18033688011112042f : 1.0f;   // log2(e)/8
#pragma unroll
        for (int n = 0; n < 4; ++n) {
            const int j = col0 + wcol + n * 16 + lr;
            const int h = j >> 6, dh = j & 63;
#pragma unroll
            for (int m = 0; m < 4; ++m)
#pragma unroll
                for (int r = 0; r < 4; ++r) {
                    const int i = row0 + wrow + m * 16 + lg * 4 + r;
                    const int b = i >> 11, s = i & 2047;
                    outp[(((size_t)b * 12 + h) * 2048 + s) * 64 + dh] = bfbits(acc[zz][m][n][r] * scl);
                }
        }
    }
    {
#pragma unroll
        for (int n = 0; n < 4; ++n) {
            const int j = col0 + wcol + n * 16 + lr;
            const int h = j >> 6, dh = j & 63;
#pragma unroll
            for (int m = 0; m < 4; ++m) {
                const int i0 = row0 + wrow + m * 16 + lg * 4;
                const int b = i0 >> 11, s0 = i0 & 2047;
                u16x4 pk;
#pragma unroll
                for (int r = 0; r < 4; ++r) pk[r] = bfbits(acc[2][m][n][r]);
                *(u16x4*)&vTo[(((size_t)b * 12 + h) * 64 + dh) * 2048 + s0] = pk;
            }
        }
    }
}

// ---------------------------------------------------------------- causal flash attention
// (R7/R15 form — session best) Fixed-max softmax: P = exp2(S'), per-lane partial row-sums,
// one reduce at end. P routed through transposed LDS [kv][16 q] with packed b64 writes +
// ds_read_b64_tr_b16 re-fragment (intrinsic MFMAs only — compiler handles hazards).
template<bool DIAG>
__device__ __forceinline__ void attn_step(
    const bf16x8* aq, f32x4* o, float* lrow,
    const u16* __restrict__ Ksb, const u16* __restrict__ Vsb, u16* __restrict__ PT,
    int kvb, int qg0, int lr, int lg)
{
    // S = Q K^T  (q = lg*4+r, kv = n*16+lr)
    f32x4 sacc[4];
#pragma unroll
    for (int n = 0; n < 4; ++n)
#pragma unroll
        for (int j = 0; j < 4; ++j) sacc[n][j] = 0.f;
    __builtin_amdgcn_s_setprio(1);
#pragma unroll
    for (int kk = 0; kk < 2; ++kk)
#pragma unroll
        for (int n = 0; n < 4; ++n) {
            const int row = n * 16 + lr;
            const int p = (kk * 4 + lg) ^ (row & 7);
            bf16x8 bk = *(const bf16x8*)&Ksb[row * 64 + p * 8];
            sacc[n] = __builtin_amdgcn_mfma_f32_16x16x32_bf16(aq[kk], bk, sacc[n], 0, 0, 0);
        }
    __builtin_amdgcn_s_setprio(0);

    float pv[4][4];
#pragma unroll
    for (int r = 0; r < 4; ++r) {
        float ls = 0.f;
#pragma unroll
        for (int n = 0; n < 4; ++n) {
            float sv = sacc[n][r];
            if (DIAG && (kvb + n * 16 + lr) > qg0 + r) sv = -1e30f;   // exp2 -> 0
            const float e = __builtin_amdgcn_exp2f(sv);
            pv[r][n] = e;
            ls += e;
        }
        lrow[r] += ls;
    }

    // P^T -> LDS [kv][16 q]: fixed n, r=0..3 are q-contiguous -> one b64 write each
#pragma unroll
    for (int n = 0; n < 4; ++n) {
        u16x4 pk;
#pragma unroll
        for (int r = 0; r < 4; ++r) pk[r] = bfbits(pv[r][n]);
        *(u16x4*)&PT[(n * 16 + lr) * 16 + lg * 4] = pk;
    }

    // re-fragment via HW transpose read: lane(lr,lg) gets P[q=lr][kv=lg*8+j] per read
    u32x2 t0, t1, t2, t3;
    __attribute__((address_space(3))) u16* pb = AS3U16(PT) + lg * 128 + lr * 4;
    asm volatile("ds_read_b64_tr_b16 %0, %1" : "=v"(t0) : "v"(pb) : "memory");
    asm volatile("ds_read_b64_tr_b16 %0, %1 offset:128" : "=v"(t1) : "v"(pb) : "memory");
    asm volatile("ds_read_b64_tr_b16 %0, %1 offset:1024" : "=v"(t2) : "v"(pb) : "memory");
    asm volatile("ds_read_b64_tr_b16 %0, %1 offset:1152" : "=v"(t3) : "v"(pb) : "memory");
    asm volatile("s_waitcnt lgkmcnt(0)" ::: "memory");
    __builtin_amdgcn_sched_barrier(0);
    union { u32x2 h[2]; bf16x8 v; } ua, ub;
    ua.h[0] = t0; ua.h[1] = t1;
    ub.h[0] = t2; ub.h[1] = t3;
    const bf16x8 ap0 = ua.v, ap1 = ub.v;

    __builtin_amdgcn_s_setprio(1);
#pragma unroll
    for (int n = 0; n < 4; ++n) {
        const int rowv = n * 16 + lr;
        const int p0 = (0 + lg) ^ (rowv & 7);
        const int p1 = (4 + lg) ^ (rowv & 7);
        bf16x8 bv0 = *(const bf16x8*)&Vsb[rowv * 64 + p0 * 8];
        bf16x8 bv1 = *(const bf16x8*)&Vsb[rowv * 64 + p1 * 8];
        o[n] = __builtin_amdgcn_mfma_f32_16x16x32_bf16(ap0, bv0, o[n], 0, 0, 0);
        o[n] = __builtin_amdgcn_mfma_f32_16x16x32_bf16(ap1, bv1, o[n], 0, 0, 0);
    }
    __builtin_amdgcn_s_setprio(0);
}

// Causal, pair-balanced, XCD-swizzled (each XCD owns 6 whole bh's: K/V L2-resident).
__global__ __launch_bounds__(256) void attn_kernel(
    const u16* __restrict__ q, const u16* __restrict__ k,
    const u16* __restrict__ vT, u16* __restrict__ attn)
{
    __shared__ u16 Ks[2][64 * 64];
    __shared__ u16 Vs[2][64 * 64];
    __shared__ u16 Ps[4][64 * 16];   // per-wave P^T

    // XCD swizzle (T1): lin -> (lin%8)*96 + lin/8  (bijective, 768 blocks)
    const int lin = blockIdx.x + (blockIdx.y << 4);
    const int logi = (lin & 7) * 96 + (lin >> 3);
    const int pair = logi & 15, bh = logi >> 4;

    const int qA = pair, qB = 31 - pair;   // qA <= 15 < 16 <= qB
    const int tid = threadIdx.x, lane = tid & 63, w = tid >> 6;
    const int lr = lane & 15, lg = lane >> 4;

    const u16* Kp = k + (size_t)bh * 2048 * 64;
    const u16* Vp = vT + (size_t)bh * 64 * 2048;

    const u16* QpA = q + ((size_t)bh * 2048 + qA * 64 + w * 16) * 64;
    const u16* QpB = q + ((size_t)bh * 2048 + qB * 64 + w * 16) * 64;
    bf16x8 aqA[2], aqB[2];
    aqA[0] = *(const bf16x8*)&QpA[lr * 64 + lg * 8];
    aqA[1] = *(const bf16x8*)&QpA[lr * 64 + 32 + lg * 8];
    aqB[0] = *(const bf16x8*)&QpB[lr * 64 + lg * 8];
    aqB[1] = *(const bf16x8*)&QpB[lr * 64 + 32 + lg * 8];

    f32x4 oA[4], oB[4];
    float lA[4], lB[4];
#pragma unroll
    for (int n = 0; n < 4; ++n)
#pragma unroll
        for (int j = 0; j < 4; ++j) { oA[n][j] = 0.f; oB[n][j] = 0.f; }
#pragma unroll
    for (int r = 0; r < 4; ++r) { lA[r] = 0.f; lB[r] = 0.f; }

#define STAGE(T, BUF)                                                                        \
    {                                                                                        \
        _Pragma("unroll")                                                                    \
        for (int it = 0; it < 2; ++it) {                                                     \
            const int c = it * 256 + w * 64 + lane;                                          \
            const int row = c >> 3, pc = c & 7;                                              \
            const int lc = pc ^ (row & 7);                                                   \
            GLOAD16(Kp + (size_t)((T) * 64 + row) * 64 + lc * 8, &Ks[BUF][(it * 256 + w * 64) * 8]); \
            GLOAD16(Vp + (size_t)row * 2048 + (T) * 64 + lc * 8, &Vs[BUF][(it * 256 + w * 64) * 8]); \
        }                                                                                    \
    }

    STAGE(0, 0);
    const int qg0A = qA * 64 + w * 16 + lg * 4;
    const int qg0B = qB * 64 + w * 16 + lg * 4;

    int t = 0;
    for (; t < qA; ++t) {               // both tiles, no masking
        const int cur = t & 1;
        __syncthreads();
        STAGE(t + 1, cur ^ 1);
        attn_step<false>(aqB, oB, lB, Ks[cur], Vs[cur], Ps[w], t * 64, qg0B, lr, lg);
        attn_step<false>(aqA, oA, lA, Ks[cur], Vs[cur], Ps[w], t * 64, qg0A, lr, lg);
    }
    {                                   // t == qA: A's diagonal
        const int cur = t & 1;
        __syncthreads();
        STAGE(t + 1, cur ^ 1);
        attn_step<false>(aqB, oB, lB, Ks[cur], Vs[cur], Ps[w], t * 64, qg0B, lr, lg);
        attn_step<true >(aqA, oA, lA, Ks[cur], Vs[cur], Ps[w], t * 64, qg0A, lr, lg);
        ++t;
    }
    for (; t < qB; ++t) {               // B only, no masking
        const int cur = t & 1;
        __syncthreads();
        STAGE(t + 1, cur ^ 1);
        attn_step<false>(aqB, oB, lB, Ks[cur], Vs[cur], Ps[w], t * 64, qg0B, lr, lg);
    }
    {                                   // t == qB: B's diagonal
        const int cur = t & 1;
        __syncthreads();
        attn_step<true >(aqB, oB, lB, Ks[cur], Vs[cur], Ps[w], t * 64, qg0B, lr, lg);
    }
#undef STAGE

    // single end-of-kernel cross-lane reduce of the partial row-sums (lanes lr 0..15)
#pragma unroll
    for (int r = 0; r < 4; ++r) {
#pragma unroll
        for (int off = 1; off < 16; off <<= 1) {
            lA[r] += __shfl_xor(lA[r], off);
            lB[r] += __shfl_xor(lB[r], off);
        }
        lA[r] = 1.f / lA[r];
        lB[r] = 1.f / lB[r];
    }

    const int b = bh / 12, h = bh - b * 12;
#pragma unroll
    for (int n = 0; n < 4; ++n)
#pragma unroll
        for (int r = 0; r < 4; ++r) {
            const int sA = qA * 64 + w * 16 + lg * 4 + r;
            const int sB = qB * 64 + w * 16 + lg * 4 + r;
            attn[((size_t)b * 2048 + sA) * 768 + h * 64 + n * 16 + lr] = bfbits(oA[n][r] * lA[r]);
            attn[((size_t)b * 2048 + sB) * 768 + h * 64 + n * 16 + lr] = bfbits(oB[n][r] * lB[r]);
        }
}

// ---------------------------------------------------------------- output projection + bias (f32 out)
// BM=64 x BN=128; 2-buffer counted-vmcnt + XCD remap.
__global__ __launch_bounds__(256) void gemm_out(
    const u16* __restrict__ A, const u16* __restrict__ Wo,
    const float* __restrict__ bo, float* __restrict__ out)
{
    __shared__ u16 As[2][64 * 32];
    __shared__ u16 Bs[2][128 * 32];
    const int tid = threadIdx.x;
    const int lane = tid & 63;
    const int w = tid >> 6;
    const int lr = lane & 15, lg = lane >> 4;
    const int wrow = (w >> 1) * 32, wcol = (w & 1) * 64;   // wave tile 32x64

    // XCD remap: 768 blocks; each XCD owns row-panels [xcd*16, xcd*16+16)
    const int lin = blockIdx.x + blockIdx.y * 6;
    const int xcd = lin & 7, idx = lin >> 3;      // idx in [0,96)
    const int prow = xcd * 16 + idx / 6;          // row panel 0..127 (64 rows each)
    const int bxc = idx % 6;
    const int row0 = prow * 64, col0 = bxc * 128;

    f32x4 acc[2][4];
#pragma unroll
    for (int m = 0; m < 2; ++m)
#pragma unroll
        for (int n = 0; n < 4; ++n)
#pragma unroll
            for (int j = 0; j < 4; ++j) acc[m][n][j] = 0.f;

#define OSTAGE(KT)                                                                                 \
    {                                                                                              \
        const int buf_ = (KT) & 1;                                                                 \
        {   /* A tile: 64x32 = one gload */                                                        \
            const int c = w * 64 + lane;                                                           \
            const int row = c >> 2, c16 = c & 3;                                                   \
            GLOAD16(A + (size_t)(row0 + row) * 768 + (KT) * 32 + c16 * 8, &As[buf_][c * 8]);       \
        }                                                                                          \
        _Pragma("unroll")                                                                          \
        for (int it = 0; it < 2; ++it) {   /* B tile: 128x32 = two gloads */                       \
            const int c = it * 256 + w * 64 + lane;                                                \
            const int row = c >> 2, c16 = c & 3;                                                   \
            GLOAD16(Wo + (size_t)(col0 + row) * 768 + (KT) * 32 + c16 * 8, &Bs[buf_][c * 8]);      \
        }                                                                                          \
    }

#define OSTEP(KT, VN, PF)                                                                          \
    {                                                                                              \
        if (PF) OSTAGE((KT) + 1);                                                                  \
        asm volatile("s_waitcnt vmcnt(" #VN ")" ::: "memory");                                     \
        __builtin_amdgcn_s_barrier();                                                              \
        const int cur_ = (KT) & 1;                                                                 \
        bf16x8 af[2], bfr[4];                                                                      \
        _Pragma("unroll")                                                                          \
        for (int m = 0; m < 2; ++m) af[m] = *(const bf16x8*)&As[cur_][(wrow + m * 16 + lr) * 32 + lg * 8]; \
        _Pragma("unroll")                                                                          \
        for (int n = 0; n < 4; ++n) bfr[n] = *(const bf16x8*)&Bs[cur_][(wcol + n * 16 + lr) * 32 + lg * 8]; \
        asm volatile("s_waitcnt lgkmcnt(0)" ::: "memory");                                         \
        __builtin_amdgcn_sched_barrier(0);                                                         \
        __builtin_amdgcn_s_barrier();                                                              \
        _Pragma("unroll")                                                                          \
        for (int m = 0; m < 2; ++m)                                                                \
            _Pragma("unroll")                                                                      \
            for (int n = 0; n < 4; ++n)                                                            \
                acc[m][n] = __builtin_amdgcn_mfma_f32_16x16x32_bf16(af[m], bfr[n], acc[m][n], 0, 0, 0); \
    }

    OSTAGE(0);
    for (int kt = 0; kt < 23; ++kt) OSTEP(kt, 3, true);
    OSTEP(23, 0, false);
#undef OSTEP
#undef OSTAGE

#pragma unroll
    for (int n = 0; n < 4; ++n) {
        const int j = col0 + wcol + n * 16 + lr;
        const float bj = bo[j];
#pragma unroll
        for (int m = 0; m < 2; ++m)
#pragma unroll
            for (int r = 0; r < 4; ++r) {
                const int i = row0 + wrow + m * 16 + lg * 4 + r;
                out[(size_t)i * 768 + j] = acc[m][n][r] + bj;
            }
    }
}

// ---------------------------------------------------------------- launch
extern "C" void kernel_launch(void* const* d_in, const int* in_sizes, int n_in,
                              void* d_out, int out_size, void* d_ws, size_t ws_size,
                              hipStream_t stream) {
    const float* x  = (const float*)d_in[0];
    const float* Wq = (const float*)d_in[1];
    const float* Wk = (const float*)d_in[2];
    const float* Wv = (const float*)d_in[3];
    const float* Wo = (const float*)d_in[4];
    const float* bo = (const float*)d_in[5];
    float* out = (float*)d_out;

    // workspace layout (bf16 elements)
    const size_t NX = 6291456;   // 8192*768
    const size_t NW = 589824;    // 768*768
    if (ws_size < (NX * 4 + NW * 4 + NX) * sizeof(u16)) return;
    u16* ws  = (u16*)d_ws;
    u16* xb  = ws;
    u16* wqb = xb  + NX;
    u16* wkb = wqb + NW;
    u16* wvb = wkb + NW;
    u16* wob = wvb + NW;
    u16* qb_ = wob + NW;
    u16* kb_ = qb_ + NX;
    u16* vtb = kb_ + NX;
    u16* ab_ = vtb + NX;

    cast_all<<<6144 + 2304, 256, 0, stream>>>(x, Wq, Wk, Wv, Wo, xb, wqb, wkb, wvb, wob);

    gemm_qkv<<<dim3(6, 64), 256, 0, stream>>>(xb, wqb, wkb, wvb, qb_, kb_, vtb);
    attn_kernel<<<dim3(16, 48), 256, 0, stream>>>(qb_, kb_, vtb, ab_);
    gemm_out<<<dim3(6, 128), 256, 0, stream>>>(ab_, wob, bo, out);
}